// Round 4
// baseline (382.038 us; speedup 1.0000x reference)
//
#include <hip/hip_runtime.h>
#include <hip/hip_bf16.h>
#include <math.h>

#define G_HID 16
#define S_HID 10
#define D 128
#define MAX_STEP 4
#define NEG 0.01f
#define SCAN_TILE 1024

typedef __attribute__((ext_vector_type(8))) short short8;
typedef __attribute__((ext_vector_type(4))) float f32x4;

__device__ __forceinline__ float leaky_f(float v){ return v >= 0.f ? v : NEG*v; }
__device__ __forceinline__ unsigned short f2bf(float f){
    unsigned int u = __float_as_uint(f);
    u = (u + 0x7FFFu + ((u>>16)&1u)) >> 16;
    return (unsigned short)u;
}
__device__ __forceinline__ float bf_lo(unsigned int v){ return __uint_as_float(v << 16); }
__device__ __forceinline__ float bf_hi(unsigned int v){ return __uint_as_float(v & 0xFFFF0000u); }

// ---------------- prep: A, z-chain, pack z into MFMA A-fragment layout ----------------
__global__ void prep_kernel(const float* __restrict__ hidden_adj,   // [16][45]
                            const float* __restrict__ hidden_feat,  // [16][10][128]
                            short* __restrict__ zpack)
{
    int g = blockIdx.x;
    __shared__ float Ag[S_HID][S_HID];
    __shared__ float zb[2][S_HID][D];
    int t = threadIdx.x;  // 128
    if (t < S_HID*S_HID) {
        int i = t / S_HID, j = t % S_HID;
        float v = 0.f;
        if (i < j) {
            int idx = 9*i - i*(i-1)/2 + (j - i - 1);
            v = leaky_f(hidden_adj[g*45 + idx]);
        } else if (i > j) {
            int idx = 9*j - j*(j-1)/2 + (i - j - 1);
            v = leaky_f(hidden_adj[g*45 + idx]);
        }
        Ag[i][j] = v;
    }
    for (int idx = t; idx < S_HID*D; idx += 128) {
        int s = idx / D, d = idx % D;
        zb[0][s][d] = hidden_feat[(g*S_HID + s)*D + d];
    }
    __syncthreads();
    int cur = 0;
    for (int step = 0; step < MAX_STEP; ++step) {
        if (step > 0) {
            int nxt = cur ^ 1;
            for (int idx = t; idx < S_HID*D; idx += 128) {
                int s = idx / D, d = idx % D;
                float acc = 0.f;
                #pragma unroll
                for (int u = 0; u < S_HID; ++u) acc += Ag[s][u] * zb[cur][u][d];
                zb[nxt][s][d] = acc;
            }
            cur = nxt;
            __syncthreads();
        }
        for (int idx = t; idx < S_HID*D; idx += 128) {
            int s = idx / D, k = idx % D;
            int row = g*S_HID + s;
            int tt = row >> 4, li = row & 15;
            int kt = k >> 5, q = (k >> 3) & 3, j = k & 7;
            zpack[(((step*10 + tt)*4 + kt)*64 + q*16 + li)*8 + j] = (short)f2bf(zb[cur][s][k]);
        }
        __syncthreads();
    }
}

// ---------------- pack fc_w into MFMA B-fragment layout ----------------
__global__ void wpack_kernel(const float* __restrict__ fc_w, short* __restrict__ wp){
    int idx = blockIdx.x*256 + threadIdx.x;
    if (idx >= 16384) return;
    int j = idx & 7, lane = (idx >> 3) & 63, ctkt = idx >> 9;
    int ct = ctkt & 7, kt = ctkt >> 3;
    int k   = kt*32 + (lane >> 4)*8 + j;
    int col = ct*16 + (lane & 15);
    wp[idx] = (short)f2bf(fc_w[k*D + col]);
}

// ---------------- CSR build ----------------
__global__ void count_kernel(const int* __restrict__ dst, int* __restrict__ offsets, int E){
    int e = blockIdx.x*blockDim.x + threadIdx.x;
    if (e < E) atomicAdd(&offsets[dst[e]+1], 1);
}

__global__ void scan1_kernel(int* __restrict__ data, int* __restrict__ bsums, int n){
    __shared__ int wsum[4];
    int base = blockIdx.x * SCAN_TILE + threadIdx.x*4;
    int v[4];
    #pragma unroll
    for (int j=0;j<4;++j) v[j] = (base+j < n) ? data[base+j] : 0;
    v[1]+=v[0]; v[2]+=v[1]; v[3]+=v[2];
    int lane = threadIdx.x & 63;
    int w = threadIdx.x >> 6;
    int s = v[3];
    for (int d=1; d<64; d<<=1){
        int o = __shfl_up(s, d);
        if (lane >= d) s += o;
    }
    if (lane == 63) wsum[w] = s;
    int sexc = s - v[3];
    __syncthreads();
    int woff = 0;
    for (int ww=0; ww<w; ++ww) woff += wsum[ww];
    int off = woff + sexc;
    #pragma unroll
    for (int j=0;j<4;++j) { if (base+j < n) data[base+j] = v[j] + off; }
    if (threadIdx.x == 255) bsums[blockIdx.x] = off + v[3];
}

__global__ void scan2_kernel(int* __restrict__ bsums, int nb){
    __shared__ int ws[4];
    __shared__ int carry_s;
    if (threadIdx.x == 0) carry_s = 0;
    __syncthreads();
    for (int start = 0; start < nb; start += 256){
        int i = start + (int)threadIdx.x;
        int v = (i < nb) ? bsums[i] : 0;
        int lane = threadIdx.x & 63, w = threadIdx.x >> 6;
        int s = v;
        for (int d=1; d<64; d<<=1){ int o = __shfl_up(s, d); if (lane >= d) s += o; }
        if (lane == 63) ws[w] = s;
        __syncthreads();
        int woff = 0;
        for (int ww=0; ww<w; ++ww) woff += ws[ww];
        int inc = s + woff + carry_s;
        if (i < nb) bsums[i] = inc - v;
        __syncthreads();
        if (threadIdx.x == 255) carry_s = inc;
        __syncthreads();
    }
}

__global__ void scan3_kernel(int* __restrict__ data, const int* __restrict__ bsums, int n){
    int base = blockIdx.x * SCAN_TILE + threadIdx.x*4;
    int add = bsums[blockIdx.x];
    #pragma unroll
    for (int j=0;j<4;++j){ if (base+j < n) data[base+j] += add; }
}

__global__ void fill_kernel(const int* __restrict__ src, const int* __restrict__ dst,
                            int* __restrict__ cursor, int* __restrict__ csr, int E){
    int e = blockIdx.x*blockDim.x + threadIdx.x;
    if (e < E){
        int d = dst[e];
        int pos = atomicAdd(&cursor[d], 1);
        csr[pos] = src[e];
    }
}

// ======== shared device helpers for the fused step kernels ========

// slot computation for segmented pooling (first 64 threads)
__device__ __forceinline__ void compute_slots(const int* __restrict__ batch, int n0, int N,
                                              int* slots, int* slotb, int* nslots_s, int t){
    if (t < 64) {
        int gn = n0 + t;
        int b = (gn < N) ? batch[gn] : -1;
        int bprev = -1;
        if (t > 0) bprev = (gn-1 < N) ? batch[gn-1] : -1;
        int flag = (t == 0 || b != bprev) ? 1 : 0;
        int s = flag;
        for (int d=1; d<64; d<<=1){ int o = __shfl_up(s, d); if (t >= d) s += o; }
        int slot = s - 1;
        slots[t] = slot;
        if (flag) slotb[slot] = b;
        if (t == 63) *nslots_s = s;
    }
}

// step phase: bw frags already in registers; z from global; writes/reads y0, pools.
template<int STEP0>
__device__ __forceinline__ void step_phase(const short8 bw[4],
                                 const short* __restrict__ zstep,
                                 float* Pf, float (*accs)[G_HID],
                                 const int* slots, const int* slotb, int nslots,
                                 uint2* __restrict__ y0buf, float* __restrict__ pooled,
                                 int stepoff, int t, int bid)
{
    int l = t & 63, w = t >> 6, li = l & 15, q = l >> 4;
    f32x4 accA[10];
    #pragma unroll
    for (int t10 = 0; t10 < 10; ++t10){
        f32x4 acc = (f32x4){0.f,0.f,0.f,0.f};
        #pragma unroll
        for (int kt = 0; kt < 4; ++kt){
            short8 az = *reinterpret_cast<const short8*>(&zstep[((t10*4 + kt)*64 + l)*8]);
            acc = __builtin_amdgcn_mfma_f32_16x16x32_bf16(az, bw[kt], acc, 0, 0, 0);
        }
        accA[t10] = acc;
    }
    size_t ybase = ((size_t)bid*4 + w)*10*64 + l;
    #pragma unroll
    for (int t10 = 0; t10 < 10; ++t10){
        f32x4 acc = accA[t10];
        float p0, p1, p2, p3;
        if (STEP0){
            uint2 st;
            st.x = (unsigned int)f2bf(acc[0]) | ((unsigned int)f2bf(acc[1]) << 16);
            st.y = (unsigned int)f2bf(acc[2]) | ((unsigned int)f2bf(acc[3]) << 16);
            y0buf[ybase + (size_t)t10*64] = st;
            p0 = acc[0]*acc[0]; p1 = acc[1]*acc[1]; p2 = acc[2]*acc[2]; p3 = acc[3]*acc[3];
        } else {
            uint2 v = y0buf[ybase + (size_t)t10*64];
            p0 = acc[0]*bf_lo(v.x); p1 = acc[1]*bf_hi(v.x);
            p2 = acc[2]*bf_lo(v.y); p3 = acc[3]*bf_hi(v.y);
        }
        int rb = (t10*16 + q*4)*66 + w*16 + li;
        Pf[rb]       = p0;
        Pf[rb + 66]  = p1;
        Pf[rb + 132] = p2;
        Pf[rb + 198] = p3;
    }
    __syncthreads();
    #pragma unroll
    for (int i = 0; i < 4; ++i){
        int g = t & 15, nd = (t >> 4) + i*16;
        float c = 0.f;
        #pragma unroll
        for (int s = 0; s < S_HID; ++s) c += Pf[(g*10 + s)*66 + nd];
        atomicAdd(&accs[slots[nd]][g], c);
    }
    __syncthreads();
    for (int idx = t; idx < nslots*G_HID; idx += 256){
        int j = idx >> 4, g = idx & 15;
        int b = slotb[j];
        if (b >= 0) atomicAdd(&pooled[(size_t)b*64 + stepoff + g], accs[j][g]);
    }
}

// ---------------- fused: embed gather + fc MFMA + sigmoid + step0 ----------------
__global__ __launch_bounds__(256) void embed_step0_kernel(
        const int* __restrict__ x_idx, const float* __restrict__ poi_emb,
        const short* __restrict__ wp, const float* __restrict__ fc_b,
        const short* __restrict__ zstep, const int* __restrict__ batch,
        unsigned short* __restrict__ x0, uint2* __restrict__ y0buf,
        float* __restrict__ pooled, int N)
{
    __shared__ __align__(16) char lbuf[42240];   // xs[64][136] bf16 (17408B) then P[160][66] f32
    __shared__ float accs[64][G_HID];
    __shared__ int slots[64];
    __shared__ int slotb[64];
    __shared__ int nslots_s;
    unsigned short* xs = (unsigned short*)lbuf;
    float* Pf = (float*)lbuf;
    int n0 = blockIdx.x * 64;
    int t = threadIdx.x;  // 256

    #pragma unroll
    for (int i = 0; i < 8; ++i) {
        int idx = t + i*256;
        int row = idx >> 5, c4 = (idx & 31)*4;
        int gn = n0 + row;
        float4 v = make_float4(0.f,0.f,0.f,0.f);
        if (gn < N) v = *reinterpret_cast<const float4*>(&poi_emb[(size_t)x_idx[gn]*D + c4]);
        unsigned int p0 = (unsigned int)f2bf(v.x) | ((unsigned int)f2bf(v.y) << 16);
        unsigned int p1 = (unsigned int)f2bf(v.z) | ((unsigned int)f2bf(v.w) << 16);
        *reinterpret_cast<uint2*>(&xs[row*136 + c4]) = make_uint2(p0, p1);
    }
    #pragma unroll
    for (int i = 0; i < 4; ++i) ((float*)accs)[t + i*256] = 0.f;
    compute_slots(batch, n0, N, slots, slotb, &nslots_s, t);
    __syncthreads();

    int l = t & 63, w = t >> 6, li = l & 15, q = l >> 4;
    // fc layer: A = own wave's 16 emb rows, B = wp
    short8 a[4];
    #pragma unroll
    for (int kt = 0; kt < 4; ++kt)
        a[kt] = *reinterpret_cast<const short8*>(&xs[(w*16 + li)*136 + kt*32 + q*8]);
    f32x4 facc[8];
    #pragma unroll
    for (int ct = 0; ct < 8; ++ct) facc[ct] = (f32x4){0.f,0.f,0.f,0.f};
    #pragma unroll
    for (int kt = 0; kt < 4; ++kt){
        #pragma unroll
        for (int ct = 0; ct < 8; ++ct){
            short8 b = reinterpret_cast<const short8*>(wp)[(kt*8 + ct)*64 + l];
            facc[ct] = __builtin_amdgcn_mfma_f32_16x16x32_bf16(a[kt], b, facc[ct], 0, 0, 0);
        }
    }
    // sigmoid + writeback to own wave's rows (invalid rows -> 0)
    #pragma unroll
    for (int ct = 0; ct < 8; ++ct){
        float bias = fc_b[ct*16 + li];
        #pragma unroll
        for (int r = 0; r < 4; ++r){
            int row = w*16 + q*4 + r;
            float s = (n0 + row < N) ? 1.f/(1.f + __expf(-(facc[ct][r] + bias))) : 0.f;
            xs[row*136 + ct*16 + li] = f2bf(s);
        }
    }
    __syncthreads();
    // write x0 to global (needed by prop of step 1)
    {
        int row = t >> 2, ch = t & 3, gn = n0 + row;
        if (gn < N){
            #pragma unroll
            for (int i2 = 0; i2 < 4; ++i2){
                uint4 v = *reinterpret_cast<const uint4*>(&xs[row*136 + ch*32 + i2*8]);
                *reinterpret_cast<uint4*>(&x0[(size_t)gn*D + ch*32 + i2*8]) = v;
            }
        }
    }
    // B-frags for step0 from LDS
    short8 bw[4];
    #pragma unroll
    for (int kt = 0; kt < 4; ++kt)
        bw[kt] = *reinterpret_cast<const short8*>(&xs[(w*16 + li)*136 + kt*32 + q*8]);
    __syncthreads();   // xs fully consumed; P region free

    step_phase<1>(bw, zstep, Pf, accs, slots, slotb, nslots_s,
                  y0buf, pooled, 0, t, blockIdx.x);
}

// ---------------- fused: prop (gather-sum) + step ----------------
template<int WRITE_X>
__global__ __launch_bounds__(256) void prop_step_kernel(
        const unsigned short* __restrict__ xin, unsigned short* __restrict__ xout,
        const int* __restrict__ offsets, const int* __restrict__ csr,
        const short* __restrict__ zstep, const int* __restrict__ batch,
        uint2* __restrict__ y0buf, float* __restrict__ pooled,
        int N, int stepoff)
{
    __shared__ __align__(16) char lbuf[42240];
    __shared__ float accs[64][G_HID];
    __shared__ int slots[64];
    __shared__ int slotb[64];
    __shared__ int nslots_s;
    unsigned short* xs = (unsigned short*)lbuf;
    float* Pf = (float*)lbuf;
    int n0 = blockIdx.x * 64;
    int t = threadIdx.x;  // 256
    int l = t & 63, w = t >> 6, li = l & 15, q = l >> 4;
    int c = l & 15;

    #pragma unroll
    for (int i = 0; i < 4; ++i) ((float*)accs)[t + i*256] = 0.f;
    compute_slots(batch, n0, N, slots, slotb, &nslots_s, t);

    // prop: quarter-wave per node, 4 nodes concurrent per wave, 4 rounds
    const uint4* xi4 = (const uint4*)xin;
    for (int nn = 0; nn < 4; ++nn){
        int lrow = w*16 + nn*4 + q;
        int node = n0 + lrow;
        float a[8];
        #pragma unroll
        for (int j=0;j<8;++j) a[j] = 0.f;
        if (node < N){
            int beg = offsets[node], end = offsets[node+1];
            for (int base = beg; base < end; base += 16){
                int cnt = min(16, end - base);
                int myu = (base + c < end) ? csr[base + c] : 0;
                for (int ei = 0; ei < cnt; ++ei){
                    int u = __shfl(myu, (q<<4) + ei);
                    uint4 va = xi4[(size_t)u*16 + c];
                    a[0] += bf_lo(va.x); a[1] += bf_hi(va.x);
                    a[2] += bf_lo(va.y); a[3] += bf_hi(va.y);
                    a[4] += bf_lo(va.z); a[5] += bf_hi(va.z);
                    a[6] += bf_lo(va.w); a[7] += bf_hi(va.w);
                }
            }
        }
        uint4 o;
        o.x = (unsigned int)f2bf(a[0]) | ((unsigned int)f2bf(a[1]) << 16);
        o.y = (unsigned int)f2bf(a[2]) | ((unsigned int)f2bf(a[3]) << 16);
        o.z = (unsigned int)f2bf(a[4]) | ((unsigned int)f2bf(a[5]) << 16);
        o.w = (unsigned int)f2bf(a[6]) | ((unsigned int)f2bf(a[7]) << 16);
        *reinterpret_cast<uint4*>(&xs[lrow*136 + c*8]) = o;
        if (WRITE_X && node < N) ((uint4*)xout)[(size_t)node*16 + c] = o;
    }
    __syncthreads();

    short8 bw[4];
    #pragma unroll
    for (int kt = 0; kt < 4; ++kt)
        bw[kt] = *reinterpret_cast<const short8*>(&xs[(w*16 + li)*136 + kt*32 + q*8]);
    __syncthreads();   // xs consumed; P region free

    step_phase<0>(bw, zstep, Pf, accs, slots, slotb, nslots_s,
                  y0buf, pooled, stepoff, t, blockIdx.x);
}

// ---------------- out = leaky(pooled @ mlp_w + mlp_b) ----------------
__global__ void out_kernel(const float* __restrict__ pooled, const float* __restrict__ mlp_w,
                           const float* __restrict__ mlp_b, float* __restrict__ out, int B){
    __shared__ float row[64];
    int b = blockIdx.x;
    int t = threadIdx.x;  // 128
    if (t < 64) row[t] = pooled[(size_t)b*64 + t];
    __syncthreads();
    float acc = mlp_b[t];
    for (int j=0;j<64;++j) acc += row[j]*mlp_w[j*D + t];
    out[(size_t)b*D + t] = leaky_f(acc);
}

extern "C" void kernel_launch(void* const* d_in, const int* in_sizes, int n_in,
                              void* d_out, int out_size, void* d_ws, size_t ws_size,
                              hipStream_t stream)
{
    const int*   x_idx = (const int*)d_in[0];
    const int*   edge  = (const int*)d_in[1];
    const int*   batch = (const int*)d_in[2];
    const float* poi   = (const float*)d_in[3];
    const float* fc_w  = (const float*)d_in[4];
    const float* fc_b  = (const float*)d_in[5];
    const float* adj   = (const float*)d_in[6];
    const float* feat  = (const float*)d_in[7];
    const float* mlp_w = (const float*)d_in[8];
    const float* mlp_b = (const float*)d_in[9];
    float* out = (float*)d_out;

    int N = in_sizes[0];
    int E = in_sizes[1] / 2;
    int B = out_size / D;
    int sblk = (N + 63) / 64;
    size_t NP = (size_t)sblk * 64;

    char* p = (char*)d_ws;
    auto alloc = [&](size_t bytes)->char* {
        char* r = p;
        p += (bytes + 255) & ~(size_t)255;
        return r;
    };
    unsigned short* x0 = (unsigned short*)alloc(NP*D*2);
    unsigned short* xa = (unsigned short*)alloc(NP*D*2);
    unsigned short* xb = (unsigned short*)alloc(NP*D*2);
    uint2* y0buf       = (uint2*)alloc(NP*160*2);           // bf16 zx in fragment layout
    float* pooled      = (float*)alloc((size_t)B*64*4);
    short* zpack       = (short*)alloc((size_t)MAX_STEP*20480*2);
    short* wp          = (short*)alloc((size_t)16384*2);
    int*   offsets     = (int*)alloc((size_t)(N+1)*4);
    int*   cursor      = (int*)alloc((size_t)N*4);
    int*   csr         = (int*)alloc((size_t)E*4);
    int*   bsums       = (int*)alloc(4096);

    const int* srcp = edge;
    const int* dstp = edge + E;

    hipMemsetAsync(offsets, 0, (size_t)(N+1)*4, stream);
    hipMemsetAsync(pooled, 0, (size_t)B*64*4, stream);

    prep_kernel<<<G_HID, 128, 0, stream>>>(adj, feat, zpack);
    wpack_kernel<<<64, 256, 0, stream>>>(fc_w, wp);

    // CSR build
    count_kernel<<<(E+255)/256, 256, 0, stream>>>(dstp, offsets, E);
    int scan_n = N + 1;
    int nblk = (scan_n + SCAN_TILE - 1) / SCAN_TILE;
    scan1_kernel<<<nblk, 256, 0, stream>>>(offsets, bsums, scan_n);
    scan2_kernel<<<1, 256, 0, stream>>>(bsums, nblk);
    scan3_kernel<<<nblk, 256, 0, stream>>>(offsets, bsums, scan_n);
    hipMemcpyAsync(cursor, offsets, (size_t)N*4, hipMemcpyDeviceToDevice, stream);
    fill_kernel<<<(E+255)/256, 256, 0, stream>>>(srcp, dstp, cursor, csr, E);

    // fused embed + step0
    embed_step0_kernel<<<sblk, 256, 0, stream>>>(x_idx, poi, wp, fc_b, zpack, batch,
                                                 x0, y0buf, pooled, N);

    // fused prop + step for steps 1..3
    const unsigned short* xin = x0;
    unsigned short* bufs[2] = {xa, xb};
    for (int i = 1; i < MAX_STEP; ++i){
        unsigned short* xout = bufs[(i-1) & 1];
        if (i < MAX_STEP-1)
            prop_step_kernel<1><<<sblk, 256, 0, stream>>>(xin, xout, offsets, csr,
                                  zpack + (size_t)i*20480, batch, y0buf, pooled, N, i*G_HID);
        else
            prop_step_kernel<0><<<sblk, 256, 0, stream>>>(xin, xout, offsets, csr,
                                  zpack + (size_t)i*20480, batch, y0buf, pooled, N, i*G_HID);
        xin = xout;
    }
    out_kernel<<<B, D, 0, stream>>>(pooled, mlp_w, mlp_b, out, B);
}